// Round 3
// baseline (2459.071 us; speedup 1.0000x reference)
//
#include <hip/hip_runtime.h>

namespace {

constexpr int H  = 64;    // hidden
constexpr int G4 = 256;   // 4*H gates
constexpr int T  = 256;   // seq len
constexpr int GB = 4;     // batch elems per block

__device__ __forceinline__ float frcp(float x) { return __builtin_amdgcn_rcpf(x); }
__device__ __forceinline__ float sgm(float x) { return frcp(1.f + __expf(-x)); }
__device__ __forceinline__ float ftanh(float x) {
  const float e = __expf(-2.f * x);
  return (1.f - e) * frcp(1.f + e);
}

// This thread's 16-float k-slice (quarter q) of row j from a row-major [256 x 64] matrix.
__device__ __forceinline__ void loadmat(float4 (&w)[4], const float* __restrict__ W,
                                        int j, int q) {
#pragma unroll
  for (int r = 0; r < 4; ++r)
    w[r] = *(const float4*)(W + j * 64 + q * 16 + r * 4);
}

// Same but from the y-part (cols 1..64) of the dec L0 [256 x 65] matrix (unaligned).
__device__ __forceinline__ void loadmat_y(float4 (&w)[4], const float* __restrict__ W,
                                          int j, int q) {
#pragma unroll
  for (int r = 0; r < 4; ++r) {
    const float* p = W + j * 65 + 1 + q * 16 + r * 4;
    w[r] = make_float4(p[0], p[1], p[2], p[3]);
  }
}

// acc[g] += W[j][16q:16q+16] . hs[g][16q:16q+16]  (weights in regs, h broadcast from LDS)
__device__ __forceinline__ void accum(const float4 (&w)[4], const float (*hs)[H], int q,
                                      float (&acc)[GB]) {
#pragma unroll
  for (int r = 0; r < 4; ++r) {
    const float4 wv = w[r];
#pragma unroll
    for (int g = 0; g < GB; ++g) {
      const float4 hv = *(const float4*)(&hs[g][q * 16 + r * 4]);
      acc[g] = fmaf(wv.x, hv.x, fmaf(wv.y, hv.y, fmaf(wv.z, hv.z, fmaf(wv.w, hv.w, acc[g]))));
    }
  }
}

__global__ __launch_bounds__(1024) void seq2seq_kernel(
    const float* __restrict__ enc_x, const float* __restrict__ dec_x,
    const float* __restrict__ eWih0, const float* __restrict__ eWhh0,
    const float* __restrict__ eb0,
    const float* __restrict__ eWih1, const float* __restrict__ eWhh1,
    const float* __restrict__ eb1,
    const float* __restrict__ eWih2, const float* __restrict__ eWhh2,
    const float* __restrict__ eb2,
    const float* __restrict__ dWih0, const float* __restrict__ dWhh0,
    const float* __restrict__ db0,
    const float* __restrict__ dWih1, const float* __restrict__ dWhh1,
    const float* __restrict__ db1,
    const float* __restrict__ dWih2, const float* __restrict__ dWhh2,
    const float* __restrict__ db2,
    const float* __restrict__ fcW, const float* __restrict__ fcb,
    float* __restrict__ out) {
  __shared__ float h[3][GB][H];      // 3 KB  hidden state
  __shared__ float yprev[GB][H];     // 1 KB  decoder feedback (y_{t-1})
  __shared__ float zp[4][GB][G4];    // 16 KB z partial sums (per k-quarter)
  __shared__ float xs[2][GB][T];     // 8 KB  staged enc_x / dec_x
  __shared__ float bias[6][G4];      // 6 KB

  const int tid = threadIdx.x;
  const int j = tid & 255;   // gate row
  const int q = tid >> 8;    // k-quarter (k in [16q, 16q+16))
  const int g2 = tid >> 6, u = tid & 63;  // update-phase mapping (tid<256)
  const int b0 = blockIdx.x * GB;

  // ---- stage x, biases; zero state ----
  for (int i = tid; i < GB * T; i += 1024) {
    ((float*)xs[0])[i] = enc_x[b0 * T + i];
    ((float*)xs[1])[i] = dec_x[b0 * T + i];
  }
  if (tid < 256) {
    bias[0][tid] = eb0[tid]; bias[1][tid] = eb1[tid]; bias[2][tid] = eb2[tid];
    bias[3][tid] = db0[tid]; bias[4][tid] = db1[tid]; bias[5][tid] = db2[tid];
  }
  for (int i = tid; i < 3 * GB * H; i += 1024) ((float*)h)[i] = 0.f;
  for (int i = tid; i < GB * H; i += 1024) ((float*)yprev)[i] = 0.f;

  float cr0 = 0.f, cr1 = 0.f, cr2 = 0.f;  // cell state (update threads, tid<256)
  const float fcw = fcW[u];
  const float fcbv = fcb[0];

  // ---- encoder weights -> registers (96 floats for 6 mats; enc uses 5) ----
  float4 w[6][4];
  loadmat(w[0], eWhh0, j, q);
  loadmat(w[1], eWih1, j, q);
  loadmat(w[2], eWhh1, j, q);
  loadmat(w[3], eWih2, j, q);
  loadmat(w[4], eWhh2, j, q);
  float xw = (q == 0) ? eWih0[j] : 0.f;  // I=1 input column

  __syncthreads();

// z-partials -> gates -> (h,c) update for layer L with bias row BROW.
#define ZUPD(L, BROW, EXTRA)                                                    \
  {                                                                             \
    _Pragma("unroll") for (int g = 0; g < GB; ++g) zp[q][g][j] = acc[g];        \
    __syncthreads();                                                            \
    if (tid < 256) {                                                            \
      float z0 = bias[BROW][u], z1 = bias[BROW][u + 64];                        \
      float z2 = bias[BROW][u + 128], z3 = bias[BROW][u + 192];                 \
      _Pragma("unroll") for (int qq = 0; qq < 4; ++qq) {                        \
        z0 += zp[qq][g2][u];       z1 += zp[qq][g2][u + 64];                    \
        z2 += zp[qq][g2][u + 128]; z3 += zp[qq][g2][u + 192];                   \
      }                                                                         \
      const float ii = sgm(z0), ff = sgm(z1), gg = ftanh(z2), oo = sgm(z3);     \
      const float cn = ff * cr##L + ii * gg;                                    \
      cr##L = cn;                                                               \
      const float hn = oo * ftanh(cn);                                          \
      h[L][g2][u] = hn;                                                         \
      EXTRA                                                                     \
    }                                                                           \
    __syncthreads();                                                            \
  }

  // ---------------- Encoder ----------------
  for (int t = 0; t < T; ++t) {
    float acc[GB];
#pragma unroll
    for (int g = 0; g < GB; ++g) acc[g] = xs[0][g][t] * xw;
    accum(w[0], h[0], q, acc);
    ZUPD(0, 0, )
#pragma unroll
    for (int g = 0; g < GB; ++g) acc[g] = 0.f;
    accum(w[1], h[0], q, acc);
    accum(w[2], h[1], q, acc);
    ZUPD(1, 1, )
#pragma unroll
    for (int g = 0; g < GB; ++g) acc[g] = 0.f;
    accum(w[3], h[1], q, acc);
    accum(w[4], h[2], q, acc);
    ZUPD(2, 2, )
  }

  // ---- decoder weights -> registers (private; no barrier needed) ----
  loadmat_y(w[0], dWih0, j, q);  // y_prev columns of [256 x 65]
  loadmat(w[1], dWhh0, j, q);
  loadmat(w[2], dWih1, j, q);
  loadmat(w[3], dWhh1, j, q);
  loadmat(w[4], dWih2, j, q);
  loadmat(w[5], dWhh2, j, q);
  xw = (q == 0) ? dWih0[j * 65] : 0.f;  // x column of concat(x, y_prev)

  // ---------------- Decoder ----------------
  for (int t = 0; t < T; ++t) {
    float acc[GB];
#pragma unroll
    for (int g = 0; g < GB; ++g) acc[g] = xs[1][g][t] * xw;
    accum(w[0], yprev, q, acc);
    accum(w[1], h[0], q, acc);
    ZUPD(0, 3, )
#pragma unroll
    for (int g = 0; g < GB; ++g) acc[g] = 0.f;
    accum(w[2], h[0], q, acc);
    accum(w[3], h[1], q, acc);
    ZUPD(1, 4, )
#pragma unroll
    for (int g = 0; g < GB; ++g) acc[g] = 0.f;
    accum(w[4], h[1], q, acc);
    accum(w[5], h[2], q, acc);
    ZUPD(2, 5, {
      yprev[g2][u] = hn;
      float p = hn * fcw;
      _Pragma("unroll") for (int o = 32; o > 0; o >>= 1) p += __shfl_down(p, o, 64);
      if (u == 0) out[(b0 + g2) * T + t] = p + fcbv;
    })
  }
#undef ZUPD
}

}  // namespace

extern "C" void kernel_launch(void* const* d_in, const int* in_sizes, int n_in,
                              void* d_out, int out_size, void* d_ws, size_t ws_size,
                              hipStream_t stream) {
  const float* enc_x = (const float*)d_in[0];
  const float* dec_x = (const float*)d_in[1];
  const float* eWih0 = (const float*)d_in[2];
  const float* eWhh0 = (const float*)d_in[3];
  const float* eb0   = (const float*)d_in[4];
  const float* eWih1 = (const float*)d_in[5];
  const float* eWhh1 = (const float*)d_in[6];
  const float* eb1   = (const float*)d_in[7];
  const float* eWih2 = (const float*)d_in[8];
  const float* eWhh2 = (const float*)d_in[9];
  const float* eb2   = (const float*)d_in[10];
  const float* dWih0 = (const float*)d_in[11];
  const float* dWhh0 = (const float*)d_in[12];
  const float* db0   = (const float*)d_in[13];
  const float* dWih1 = (const float*)d_in[14];
  const float* dWhh1 = (const float*)d_in[15];
  const float* db1   = (const float*)d_in[16];
  const float* dWih2 = (const float*)d_in[17];
  const float* dWhh2 = (const float*)d_in[18];
  const float* db2   = (const float*)d_in[19];
  const float* fcW   = (const float*)d_in[20];
  const float* fcb   = (const float*)d_in[21];
  float* out = (float*)d_out;

  seq2seq_kernel<<<dim3(256), dim3(1024), 0, stream>>>(
      enc_x, dec_x, eWih0, eWhh0, eb0, eWih1, eWhh1, eb1, eWih2, eWhh2, eb2,
      dWih0, dWhh0, db0, dWih1, dWhh1, db1, dWih2, dWhh2, db2, fcW, fcb, out);
}

// Round 4
// 2097.435 us; speedup vs baseline: 1.1724x; 1.1724x over previous
//
#include <hip/hip_runtime.h>

namespace {

typedef float v2f __attribute__((ext_vector_type(2)));

constexpr int H  = 64;    // hidden
constexpr int G4 = 256;   // 4*H gates
constexpr int T  = 256;   // seq len
constexpr int GB = 4;     // batch elems per block

__device__ __forceinline__ float frcp(float x) { return __builtin_amdgcn_rcpf(x); }
__device__ __forceinline__ float sgm(float x) { return frcp(1.f + __expf(-x)); }
__device__ __forceinline__ float ftanh(float x) {
  const float e = __expf(-2.f * x);
  return (1.f - e) * frcp(1.f + e);
}

// acc[r][g] (v2f over k-pairs) += W-rows . h[g][kb..kb+8)
__device__ __forceinline__ void accum(const v2f (&wm)[2][4], const float (*h)[H], int kb,
                                      v2f (&acc)[2][GB]) {
#pragma unroll
  for (int g = 0; g < GB; ++g) {
    const float4 a = *(const float4*)&h[g][kb];
    const float4 b = *(const float4*)&h[g][kb + 4];
    const v2f p0 = {a.x, a.y}, p1 = {a.z, a.w}, p2 = {b.x, b.y}, p3 = {b.z, b.w};
#pragma unroll
    for (int r = 0; r < 2; ++r) {
      acc[r][g] = __builtin_elementwise_fma(wm[r][0], p0, acc[r][g]);
      acc[r][g] = __builtin_elementwise_fma(wm[r][1], p1, acc[r][g]);
      acc[r][g] = __builtin_elementwise_fma(wm[r][2], p2, acc[r][g]);
      acc[r][g] = __builtin_elementwise_fma(wm[r][3], p3, acc[r][g]);
    }
  }
}

__global__ __launch_bounds__(1024, 4) void seq2seq_kernel(
    const float* __restrict__ enc_x, const float* __restrict__ dec_x,
    const float* __restrict__ eWih0, const float* __restrict__ eWhh0,
    const float* __restrict__ eb0,
    const float* __restrict__ eWih1, const float* __restrict__ eWhh1,
    const float* __restrict__ eb1,
    const float* __restrict__ eWih2, const float* __restrict__ eWhh2,
    const float* __restrict__ eb2,
    const float* __restrict__ dWih0, const float* __restrict__ dWhh0,
    const float* __restrict__ db0,
    const float* __restrict__ dWih1, const float* __restrict__ dWhh1,
    const float* __restrict__ db1,
    const float* __restrict__ dWih2, const float* __restrict__ dWhh2,
    const float* __restrict__ db2,
    const float* __restrict__ fcW, const float* __restrict__ fcb,
    float* __restrict__ out) {
  __shared__ float hs[3][GB][H];       // 3 KB   hidden state [layer][g][k]
  __shared__ float yp[GB][H];          // 1 KB   decoder feedback
  __shared__ float xs[2][GB][T];       // 8 KB   staged enc_x / dec_x
  __shared__ float zp[8][GB][4][64];   // 32 KB  z partials [kg][g][gate m][u]
  __shared__ float bias[6][G4];        // 6 KB

  const int tid = threadIdx.x;
  const int p  = tid & 127;  // row-pair id
  const int kg = tid >> 7;   // k-octet (k in [8kg, 8kg+8)) -- wave-uniform
  const int uw = p & 63;     // unit of this row-pair
  const int mt = p >> 6;     // 0: gates (i,f)  1: gates (g,o) -- wave-uniform
  const int r0 = uw + 128 * mt, r1 = r0 + 64;  // the two owned gate rows
  const int kb = kg * 8;
  const int g2 = (tid >> 6) & 3, u = tid & 63;  // update mapping (tid<256)
  const int b0 = blockIdx.x * GB;

  // ---- stage x, biases; zero state ----
  for (int i = tid; i < GB * T; i += 1024) {
    ((float*)xs[0])[i] = enc_x[b0 * T + i];
    ((float*)xs[1])[i] = dec_x[b0 * T + i];
  }
  if (tid < 256) {
    bias[0][tid] = eb0[tid]; bias[1][tid] = eb1[tid]; bias[2][tid] = eb2[tid];
    bias[3][tid] = db0[tid]; bias[4][tid] = db1[tid]; bias[5][tid] = db2[tid];
  }
  for (int i = tid; i < 3 * GB * H; i += 1024) ((float*)hs)[i] = 0.f;
  for (int i = tid; i < GB * H; i += 1024) ((float*)yp)[i] = 0.f;

  float cr0 = 0.f, cr1 = 0.f, cr2 = 0.f;  // cell state (update threads)
  const float fcw = fcW[u];
  const float fcbv = fcb[0];

  // ---- weights -> registers: 6 mats x 2 rows x 4 k-pairs = 96 floats ----
  v2f w[6][2][4];
#define LDW(M, W, LD, OFF)                                                  \
  {                                                                         \
    const float* s0 = (W) + r0 * (LD) + (OFF) + kb;                         \
    const float* s1 = (W) + r1 * (LD) + (OFF) + kb;                         \
    _Pragma("unroll") for (int q2 = 0; q2 < 4; ++q2) {                      \
      w[M][0][q2] = (v2f){s0[2 * q2], s0[2 * q2 + 1]};                      \
      w[M][1][q2] = (v2f){s1[2 * q2], s1[2 * q2 + 1]};                      \
    }                                                                       \
  }
  LDW(0, eWhh0, 64, 0)
  LDW(1, eWih1, 64, 0)
  LDW(2, eWhh1, 64, 0)
  LDW(3, eWih2, 64, 0)
  LDW(4, eWhh2, 64, 0)
  float xw0 = eWih0[r0], xw1 = eWih0[r1];  // I=1 input column

  __syncthreads();

// z partials -> gates -> (h,c) update for layer L, bias row BROW.
#define ZUPD(L, BROW, EXTRA)                                                \
  {                                                                         \
    _Pragma("unroll") for (int g = 0; g < GB; ++g) {                        \
      zp[kg][g][2 * mt][uw]     = acc[0][g].x + acc[0][g].y;                \
      zp[kg][g][2 * mt + 1][uw] = acc[1][g].x + acc[1][g].y;                \
    }                                                                       \
    __syncthreads();                                                        \
    if (tid < 256) {                                                        \
      float z[4];                                                           \
      _Pragma("unroll") for (int m = 0; m < 4; ++m) {                       \
        float s = bias[BROW][m * 64 + u];                                   \
        _Pragma("unroll") for (int k2 = 0; k2 < 8; ++k2)                    \
            s += zp[k2][g2][m][u];                                          \
        z[m] = s;                                                           \
      }                                                                     \
      const float ii = sgm(z[0]), ff = sgm(z[1]);                           \
      const float gg = ftanh(z[2]), oo = sgm(z[3]);                         \
      const float cn = ff * cr##L + ii * gg;                                \
      cr##L = cn;                                                           \
      const float hn = oo * ftanh(cn);                                      \
      hs[L][g2][u] = hn;                                                    \
      EXTRA                                                                 \
    }                                                                       \
    __syncthreads();                                                        \
  }

#define ZACC_CLEAR                                                          \
  v2f acc[2][GB];                                                           \
  _Pragma("unroll") for (int r = 0; r < 2; ++r)                             \
      _Pragma("unroll") for (int g = 0; g < GB; ++g) acc[r][g] = (v2f)(0.f);

  // ---------------- Encoder ----------------
  for (int t = 0; t < T; ++t) {
    {
      ZACC_CLEAR
      accum(w[0], hs[0], kb, acc);
      if (kg == 0) {  // wave-uniform: fold x * Wih0 column
#pragma unroll
        for (int g = 0; g < GB; ++g) {
          const float xv = xs[0][g][t];
          acc[0][g].x += xw0 * xv;
          acc[1][g].x += xw1 * xv;
        }
      }
      ZUPD(0, 0, )
    }
    {
      ZACC_CLEAR
      accum(w[1], hs[0], kb, acc);
      accum(w[2], hs[1], kb, acc);
      ZUPD(1, 1, )
    }
    {
      ZACC_CLEAR
      accum(w[3], hs[1], kb, acc);
      accum(w[4], hs[2], kb, acc);
      ZUPD(2, 2, )
    }
  }

  // ---- decoder weights -> registers (private; no barrier needed) ----
  LDW(0, dWih0, 65, 1)   // y_prev columns of [256 x 65]
  LDW(1, dWhh0, 64, 0)
  LDW(2, dWih1, 64, 0)
  LDW(3, dWhh1, 64, 0)
  LDW(4, dWih2, 64, 0)
  LDW(5, dWhh2, 64, 0)
  xw0 = dWih0[r0 * 65];  // x column of concat(x, y_prev)
  xw1 = dWih0[r1 * 65];

  // ---------------- Decoder ----------------
  for (int t = 0; t < T; ++t) {
    {
      ZACC_CLEAR
      accum(w[0], yp, kb, acc);
      accum(w[1], hs[0], kb, acc);
      if (kg == 0) {
#pragma unroll
        for (int g = 0; g < GB; ++g) {
          const float xv = xs[1][g][t];
          acc[0][g].x += xw0 * xv;
          acc[1][g].x += xw1 * xv;
        }
      }
      ZUPD(0, 3, )
    }
    {
      ZACC_CLEAR
      accum(w[2], hs[0], kb, acc);
      accum(w[3], hs[1], kb, acc);
      ZUPD(1, 4, )
    }
    {
      ZACC_CLEAR
      accum(w[4], hs[1], kb, acc);
      accum(w[5], hs[2], kb, acc);
      ZUPD(2, 5, {
        yp[g2][u] = hn;
        float pr = hn * fcw;
        _Pragma("unroll") for (int o = 32; o > 0; o >>= 1)
            pr += __shfl_down(pr, o, 64);
        if (u == 0) out[(b0 + g2) * T + t] = pr + fcbv;
      })
    }
  }
#undef ZUPD
#undef ZACC_CLEAR
#undef LDW
}

}  // namespace

extern "C" void kernel_launch(void* const* d_in, const int* in_sizes, int n_in,
                              void* d_out, int out_size, void* d_ws, size_t ws_size,
                              hipStream_t stream) {
  const float* enc_x = (const float*)d_in[0];
  const float* dec_x = (const float*)d_in[1];
  const float* eWih0 = (const float*)d_in[2];
  const float* eWhh0 = (const float*)d_in[3];
  const float* eb0   = (const float*)d_in[4];
  const float* eWih1 = (const float*)d_in[5];
  const float* eWhh1 = (const float*)d_in[6];
  const float* eb1   = (const float*)d_in[7];
  const float* eWih2 = (const float*)d_in[8];
  const float* eWhh2 = (const float*)d_in[9];
  const float* eb2   = (const float*)d_in[10];
  const float* dWih0 = (const float*)d_in[11];
  const float* dWhh0 = (const float*)d_in[12];
  const float* db0   = (const float*)d_in[13];
  const float* dWih1 = (const float*)d_in[14];
  const float* dWhh1 = (const float*)d_in[15];
  const float* db1   = (const float*)d_in[16];
  const float* dWih2 = (const float*)d_in[17];
  const float* dWhh2 = (const float*)d_in[18];
  const float* db2   = (const float*)d_in[19];
  const float* fcW   = (const float*)d_in[20];
  const float* fcb   = (const float*)d_in[21];
  float* out = (float*)d_out;

  seq2seq_kernel<<<dim3(256), dim3(1024), 0, stream>>>(
      enc_x, dec_x, eWih0, eWhh0, eb0, eWih1, eWhh1, eb1, eWih2, eWhh2, eb2,
      dWih0, dWhh0, db0, dWih1, dWhh1, db1, dWih2, dWhh2, db2, fcW, fcb, out);
}

// Round 5
// 1829.530 us; speedup vs baseline: 1.3441x; 1.1464x over previous
//
#include <hip/hip_runtime.h>

namespace {

typedef float v2f __attribute__((ext_vector_type(2)));

constexpr int H  = 64;    // hidden
constexpr int G4 = 256;   // 4*H gates
constexpr int T  = 256;   // seq len
constexpr int GB = 4;     // batch elems per block

__device__ __forceinline__ float frcp(float x) { return __builtin_amdgcn_rcpf(x); }
__device__ __forceinline__ float sgm(float x) { return frcp(1.f + __expf(-x)); }
__device__ __forceinline__ float ftanh(float x) {
  const float e = __expf(-2.f * x);
  return (1.f - e) * frcp(1.f + e);
}

// acc[r][gi] += W-rows . h[g0+gi][kb..kb+8)   (2 batch elems at a time)
__device__ __forceinline__ void accum2(const v2f (&wm)[2][4], const float (*h)[H], int kb,
                                       int g0, v2f (&acc)[2][2]) {
#pragma unroll
  for (int gi = 0; gi < 2; ++gi) {
    const float4 a = *(const float4*)&h[g0 + gi][kb];
    const float4 b = *(const float4*)&h[g0 + gi][kb + 4];
    const v2f p0 = {a.x, a.y}, p1 = {a.z, a.w}, p2 = {b.x, b.y}, p3 = {b.z, b.w};
#pragma unroll
    for (int r = 0; r < 2; ++r) {
      acc[r][gi] = __builtin_elementwise_fma(wm[r][0], p0, acc[r][gi]);
      acc[r][gi] = __builtin_elementwise_fma(wm[r][1], p1, acc[r][gi]);
      acc[r][gi] = __builtin_elementwise_fma(wm[r][2], p2, acc[r][gi]);
      acc[r][gi] = __builtin_elementwise_fma(wm[r][3], p3, acc[r][gi]);
    }
  }
}

__global__ __launch_bounds__(1024, 1) void seq2seq_kernel(
    const float* __restrict__ enc_x, const float* __restrict__ dec_x,
    const float* __restrict__ eWih0, const float* __restrict__ eWhh0,
    const float* __restrict__ eb0,
    const float* __restrict__ eWih1, const float* __restrict__ eWhh1,
    const float* __restrict__ eb1,
    const float* __restrict__ eWih2, const float* __restrict__ eWhh2,
    const float* __restrict__ eb2,
    const float* __restrict__ dWih0, const float* __restrict__ dWhh0,
    const float* __restrict__ db0,
    const float* __restrict__ dWih1, const float* __restrict__ dWhh1,
    const float* __restrict__ db1,
    const float* __restrict__ dWih2, const float* __restrict__ dWhh2,
    const float* __restrict__ db2,
    const float* __restrict__ fcW, const float* __restrict__ fcb,
    float* __restrict__ out) {
  __shared__ float hs[3][GB][H];       // 3 KB   hidden state [layer][g][k]
  __shared__ float yp[GB][H];          // 1 KB   decoder feedback
  __shared__ float xs[2][GB][T];       // 8 KB   staged enc_x / dec_x
  __shared__ float zp[8][GB][4][64];   // 32 KB  z partials [kg][g][gate m][u]
  __shared__ float bias[6][G4];        // 6 KB

  const int tid = threadIdx.x;
  const int p  = tid & 127;  // row-pair id
  const int kg = tid >> 7;   // k-octet (k in [8kg, 8kg+8)) -- wave-uniform
  const int uw = p & 63;     // unit of this row-pair
  const int mt = p >> 6;     // 0: gates (i,f)  1: gates (g,o) -- wave-uniform
  const int r0 = uw + 128 * mt, r1 = r0 + 64;  // the two owned gate rows
  const int kb = kg * 8;
  const int g2 = (tid >> 6) & 3, u = tid & 63;  // update mapping (tid<256)
  const int b0 = blockIdx.x * GB;

  // ---- stage x, biases; zero state ----
  for (int i = tid; i < GB * T; i += 1024) {
    ((float*)xs[0])[i] = enc_x[b0 * T + i];
    ((float*)xs[1])[i] = dec_x[b0 * T + i];
  }
  if (tid < 256) {
    bias[0][tid] = eb0[tid]; bias[1][tid] = eb1[tid]; bias[2][tid] = eb2[tid];
    bias[3][tid] = db0[tid]; bias[4][tid] = db1[tid]; bias[5][tid] = db2[tid];
  }
  for (int i = tid; i < 3 * GB * H; i += 1024) ((float*)hs)[i] = 0.f;
  for (int i = tid; i < GB * H; i += 1024) ((float*)yp)[i] = 0.f;

  float cr0 = 0.f, cr1 = 0.f, cr2 = 0.f;  // cell state (update threads)
  const float fcw = fcW[u];
  const float fcbv = fcb[0];

  // ---- weights -> registers: 6 mats x 2 rows x 4 k-pairs = 96 floats ----
  v2f w[6][2][4];
#define LDW(M, W, LD, OFF)                                                  \
  {                                                                         \
    const float* s0 = (W) + r0 * (LD) + (OFF) + kb;                         \
    const float* s1 = (W) + r1 * (LD) + (OFF) + kb;                         \
    _Pragma("unroll") for (int q2 = 0; q2 < 4; ++q2) {                      \
      w[M][0][q2] = (v2f){s0[2 * q2], s0[2 * q2 + 1]};                      \
      w[M][1][q2] = (v2f){s1[2 * q2], s1[2 * q2 + 1]};                      \
    }                                                                       \
  }
  LDW(0, eWhh0, 64, 0)
  LDW(1, eWih1, 64, 0)
  LDW(2, eWhh1, 64, 0)
  LDW(3, eWih2, 64, 0)
  LDW(4, eWhh2, 64, 0)
  float xw0 = eWih0[r0], xw1 = eWih0[r1];  // I=1 input column

  __syncthreads();

// store this batch-pair's z partials
#define ZSTORE(gp)                                                          \
  _Pragma("unroll") for (int gi = 0; gi < 2; ++gi) {                        \
    zp[kg][2 * (gp) + gi][2 * mt][uw]     = acc[0][gi].x + acc[0][gi].y;    \
    zp[kg][2 * (gp) + gi][2 * mt + 1][uw] = acc[1][gi].x + acc[1][gi].y;    \
  }

#define ACLR                                                                \
  v2f acc[2][2];                                                            \
  acc[0][0] = (v2f)(0.f); acc[0][1] = (v2f)(0.f);                           \
  acc[1][0] = (v2f)(0.f); acc[1][1] = (v2f)(0.f);

// barrier -> gate reduction -> (h,c) update for layer L, bias row BROW.
#define ZUPD(L, BROW, EXTRA)                                                \
  __syncthreads();                                                          \
  if (tid < 256) {                                                          \
    float z[4];                                                             \
    _Pragma("unroll") for (int m = 0; m < 4; ++m) {                         \
      float s = bias[BROW][m * 64 + u];                                     \
      _Pragma("unroll") for (int k2 = 0; k2 < 8; ++k2)                      \
          s += zp[k2][g2][m][u];                                            \
      z[m] = s;                                                             \
    }                                                                       \
    const float ii = sgm(z[0]), ff = sgm(z[1]);                             \
    const float gg = ftanh(z[2]), oo = sgm(z[3]);                           \
    const float cn = ff * cr##L + ii * gg;                                  \
    cr##L = cn;                                                             \
    const float hn = oo * ftanh(cn);                                        \
    hs[L][g2][u] = hn;                                                      \
    EXTRA                                                                   \
  }                                                                         \
  __syncthreads();

  // ---------------- Encoder ----------------
  for (int t = 0; t < T; ++t) {
#pragma clang loop unroll(disable)
    for (int gp = 0; gp < 2; ++gp) {
      ACLR
      accum2(w[0], hs[0], kb, 2 * gp, acc);
      if (kg == 0) {
#pragma unroll
        for (int gi = 0; gi < 2; ++gi) {
          const float xv = xs[0][2 * gp + gi][t];
          acc[0][gi].x += xw0 * xv;
          acc[1][gi].x += xw1 * xv;
        }
      }
      ZSTORE(gp)
    }
    ZUPD(0, 0, )
#pragma clang loop unroll(disable)
    for (int gp = 0; gp < 2; ++gp) {
      ACLR
      accum2(w[1], hs[0], kb, 2 * gp, acc);
      accum2(w[2], hs[1], kb, 2 * gp, acc);
      ZSTORE(gp)
    }
    ZUPD(1, 1, )
#pragma clang loop unroll(disable)
    for (int gp = 0; gp < 2; ++gp) {
      ACLR
      accum2(w[3], hs[1], kb, 2 * gp, acc);
      accum2(w[4], hs[2], kb, 2 * gp, acc);
      ZSTORE(gp)
    }
    ZUPD(2, 2, )
  }

  // ---- decoder weights -> registers (private; no barrier needed) ----
  LDW(0, dWih0, 65, 1)   // y_prev columns of [256 x 65]
  LDW(1, dWhh0, 64, 0)
  LDW(2, dWih1, 64, 0)
  LDW(3, dWhh1, 64, 0)
  LDW(4, dWih2, 64, 0)
  LDW(5, dWhh2, 64, 0)
  xw0 = dWih0[r0 * 65];  // x column of concat(x, y_prev)
  xw1 = dWih0[r1 * 65];

  // ---------------- Decoder ----------------
  for (int t = 0; t < T; ++t) {
#pragma clang loop unroll(disable)
    for (int gp = 0; gp < 2; ++gp) {
      ACLR
      accum2(w[0], yp, kb, 2 * gp, acc);
      accum2(w[1], hs[0], kb, 2 * gp, acc);
      if (kg == 0) {
#pragma unroll
        for (int gi = 0; gi < 2; ++gi) {
          const float xv = xs[1][2 * gp + gi][t];
          acc[0][gi].x += xw0 * xv;
          acc[1][gi].x += xw1 * xv;
        }
      }
      ZSTORE(gp)
    }
    ZUPD(0, 3, )
#pragma clang loop unroll(disable)
    for (int gp = 0; gp < 2; ++gp) {
      ACLR
      accum2(w[2], hs[0], kb, 2 * gp, acc);
      accum2(w[3], hs[1], kb, 2 * gp, acc);
      ZSTORE(gp)
    }
    ZUPD(1, 4, )
#pragma clang loop unroll(disable)
    for (int gp = 0; gp < 2; ++gp) {
      ACLR
      accum2(w[4], hs[1], kb, 2 * gp, acc);
      accum2(w[5], hs[2], kb, 2 * gp, acc);
      ZSTORE(gp)
    }
    ZUPD(2, 5, {
      yp[g2][u] = hn;
      float pr = hn * fcw;
      _Pragma("unroll") for (int o = 32; o > 0; o >>= 1)
          pr += __shfl_down(pr, o, 64);
      if (u == 0) out[(b0 + g2) * T + t] = pr + fcbv;
    })
  }
#undef ZUPD
#undef ZSTORE
#undef ACLR
#undef LDW
}

}  // namespace

extern "C" void kernel_launch(void* const* d_in, const int* in_sizes, int n_in,
                              void* d_out, int out_size, void* d_ws, size_t ws_size,
                              hipStream_t stream) {
  const float* enc_x = (const float*)d_in[0];
  const float* dec_x = (const float*)d_in[1];
  const float* eWih0 = (const float*)d_in[2];
  const float* eWhh0 = (const float*)d_in[3];
  const float* eb0   = (const float*)d_in[4];
  const float* eWih1 = (const float*)d_in[5];
  const float* eWhh1 = (const float*)d_in[6];
  const float* eb1   = (const float*)d_in[7];
  const float* eWih2 = (const float*)d_in[8];
  const float* eWhh2 = (const float*)d_in[9];
  const float* eb2   = (const float*)d_in[10];
  const float* dWih0 = (const float*)d_in[11];
  const float* dWhh0 = (const float*)d_in[12];
  const float* db0   = (const float*)d_in[13];
  const float* dWih1 = (const float*)d_in[14];
  const float* dWhh1 = (const float*)d_in[15];
  const float* db1   = (const float*)d_in[16];
  const float* dWih2 = (const float*)d_in[17];
  const float* dWhh2 = (const float*)d_in[18];
  const float* db2   = (const float*)d_in[19];
  const float* fcW   = (const float*)d_in[20];
  const float* fcb   = (const float*)d_in[21];
  float* out = (float*)d_out;

  seq2seq_kernel<<<dim3(256), dim3(1024), 0, stream>>>(
      enc_x, dec_x, eWih0, eWhh0, eb0, eWih1, eWhh1, eb1, eWih2, eWhh2, eb2,
      dWih0, dWhh0, db0, dWih1, dWhh1, db1, dWih2, dWhh2, db2, fcW, fcb, out);
}